// Round 9
// baseline (148.303 us; speedup 1.0000x reference)
//
#include <hip/hip_runtime.h>

// LGAN layer on a fixed 8-ring graph, N=20000, D=128, MH=256.
// R9: edge-MLP stage 1 factored through G = h@We1 (linear before ReLU):
//       h_e = relu(G[u]+G[v]+b1) @ We2 + b2
//     g_gemm computes G once (20000 rows, sigma-permuted cols, bf16,
//     overlaid on catb), edge_mlp is stage-2-only with We2 quarter-staged
//     in 16KB LDS phases. he stored in pi-permuted cols (64B/lane stores);
//     pi folded into Wf1 rows. aggregate/sum_layers/fuse/out as R8.

#define NN 20000
#define NE 160000
#define DD 128
#define MHD 256

typedef __attribute__((ext_vector_type(8))) short short8;
typedef __attribute__((ext_vector_type(4))) short short4v;
typedef __attribute__((ext_vector_type(4))) float f32x4;

#define SWZ(row) (((row) & 7) << 3)

__device__ __forceinline__ float bf2f(short s) {
  return __builtin_bit_cast(float, (unsigned int)((unsigned short)s) << 16);
}
__device__ __forceinline__ short f2bf(float f) {
  unsigned int u = __builtin_bit_cast(unsigned int, f);
  u = (u + 0x7FFFu + ((u >> 16) & 1u)) >> 16;
  return (short)u;
}
__device__ __forceinline__ short8 zero8() {
  short8 z;
#pragma unroll
  for (int q = 0; q < 8; ++q) z[q] = 0;
  return z;
}

#define MFMA(a, b, c) __builtin_amdgcn_mfma_f32_16x16x32_bf16((a), (b), (c), 0, 0, 0)

// ============ Kernel A0: G = h @ We1, sigma-permuted bf16 columns ==========
// wqA: 4 quarters of We1, each [64 mids][128 k] chunk-swizzled (16 KB).
__global__ __launch_bounds__(256, 3) void g_gemm(
    const short* __restrict__ hbf, const short* __restrict__ wqA,
    short* __restrict__ G) {
  __shared__ __align__(16) short WS[8192];
  const int t = threadIdx.x;
  const int lane = t & 63, w = t >> 6;
  const int lr = lane & 15, lg = lane >> 4;
  const int rbase = blockIdx.x * 128 + w * 32;

  short8 xf[2][4];
#pragma unroll
  for (int rs = 0; rs < 2; ++rs) {
    int r = rbase + rs * 16 + lr;
    if (r >= NN) r = NN - 1;
    const short* hr = hbf + (size_t)r * DD;
#pragma unroll
    for (int kk = 0; kk < 4; ++kk)
      xf[rs][kk] = *(const short8*)&hr[kk * 32 + lg * 8];
  }

#pragma unroll 1
  for (int p = 0; p < 4; ++p) {
    {
      short8 stg[4];
#pragma unroll
      for (int c = 0; c < 4; ++c)
        stg[c] = *(const short8*)&wqA[p * 8192 + (c * 256 + t) * 8];
#pragma unroll
      for (int c = 0; c < 4; ++c) *(short8*)&WS[(c * 256 + t) * 8] = stg[c];
    }
    __syncthreads();
#pragma unroll
    for (int ct = 0; ct < 4; ++ct) {
      short8 aw[4];
#pragma unroll
      for (int kk = 0; kk < 4; ++kk)
        aw[kk] = *(const short8*)&WS[(ct * 16 + lr) * 128 +
                                     (((kk * 4 + lg) ^ lr) << 3)];
#pragma unroll
      for (int rs = 0; rs < 2; ++rs) {
        f32x4 a1 = {0.f, 0.f, 0.f, 0.f};
#pragma unroll
        for (int kk = 0; kk < 4; ++kk) a1 = MFMA(aw[kk], xf[rs][kk], a1);
        const int row = rbase + rs * 16 + lr;
        if (row < NN) {
          short4v o;
#pragma unroll
          for (int q = 0; q < 4; ++q) o[q] = f2bf(a1[q]);
          // logical col L = p*64 + ct*16 + 4lg + q -> slot (inverse sigma):
          const int off = p * 64 + (ct >> 1) * 32 + lg * 8 + (ct & 1) * 4;
          *(short4v*)&G[(size_t)row * 256 + off] = o;
        }
      }
    }
    __syncthreads();
  }
}

// ============ Kernel A1: h_e = relu(G[u]+G[v]+b1) @ We2 + b2 ===============
// wqB: 4 quarters of We2, each [128 o][64 slots] chunk-swz + sigma (16 KB).
// be1P[s] = be1[klog(s)]. he stored pi-permuted: col'' = lg*32+ct2*4+q.
__global__ __launch_bounds__(256, 3) void edge_mlp(
    const short* __restrict__ G, const short* __restrict__ wqB,
    const float* __restrict__ be1P, const float* __restrict__ be2,
    short* __restrict__ he) {
  __shared__ __align__(16) short WS[8192];
  const int t = threadIdx.x;
  const int lane = t & 63, w = t >> 6;
  const int lr = lane & 15, lg = lane >> 4;
  const int ebase = blockIdx.x * 128 + w * 32;

  int urow[2], vrow[2];
#pragma unroll
  for (int rs = 0; rs < 2; ++rs) {
    const int e = ebase + rs * 16 + lr;
    const int j = e / NN + 1;
    const int i = e - (j - 1) * NN;
    int v = i + j;
    if (v >= NN) v -= NN;
    urow[rs] = i;
    vrow[rs] = v;
  }

  f32x4 acc[2][8];
#pragma unroll
  for (int ct2 = 0; ct2 < 8; ++ct2) {
    const f32x4 b2 = *(const f32x4*)&be2[ct2 * 16 + 4 * lg];
    acc[0][ct2] = b2;
    acc[1][ct2] = b2;
  }

#pragma unroll 1
  for (int p = 0; p < 4; ++p) {
    {
      short8 stg[4];
#pragma unroll
      for (int c = 0; c < 4; ++c)
        stg[c] = *(const short8*)&wqB[p * 8192 + (c * 256 + t) * 8];
#pragma unroll
      for (int c = 0; c < 4; ++c) *(short8*)&WS[(c * 256 + t) * 8] = stg[c];
    }
    __syncthreads();

    short8 pa[2][2];
#pragma unroll
    for (int rs = 0; rs < 2; ++rs)
#pragma unroll
      for (int kk2 = 0; kk2 < 2; ++kk2) {
        const int so = p * 64 + kk2 * 32 + lg * 8;
        short8 gu = *(const short8*)&G[(size_t)urow[rs] * 256 + so];
        short8 gv = *(const short8*)&G[(size_t)vrow[rs] * 256 + so];
        const f32x4 ba = *(const f32x4*)&be1P[so];
        const f32x4 bb = *(const f32x4*)&be1P[so + 4];
        short8 z;
#pragma unroll
        for (int q = 0; q < 8; ++q) {
          float x = bf2f(gu[q]) + bf2f(gv[q]) + (q < 4 ? ba[q] : bb[q - 4]);
          z[q] = f2bf(x > 0.f ? x : 0.f);
        }
        pa[rs][kk2] = z;
      }

#pragma unroll
    for (int kk2 = 0; kk2 < 2; ++kk2)
#pragma unroll
      for (int ct2 = 0; ct2 < 8; ++ct2) {
        short8 aw2 = *(const short8*)&WS[(ct2 * 16 + lr) * 64 +
                                         (((kk2 * 4 + lg) ^ (lr & 7)) << 3)];
        acc[0][ct2] = MFMA(aw2, pa[0][kk2], acc[0][ct2]);
        acc[1][ct2] = MFMA(aw2, pa[1][kk2], acc[1][ct2]);
      }
    __syncthreads();
  }

  // pi-layout store: per rs one contiguous 64B run per lane
#pragma unroll
  for (int rs = 0; rs < 2; ++rs) {
    const size_t rowoff = (size_t)(ebase + rs * 16 + lr) * DD + lg * 32;
#pragma unroll
    for (int c = 0; c < 4; ++c) {
      short8 o;
#pragma unroll
      for (int hh = 0; hh < 2; ++hh)
#pragma unroll
        for (int q = 0; q < 4; ++q) o[hh * 4 + q] = f2bf(acc[rs][c * 2 + hh][q]);
      *(short8*)&he[rowoff + c * 8] = o;
    }
  }
}

// ================= Kernel B0: T8[r] = sum over 8 layers of he ==============
__global__ __launch_bounds__(256) void sum_layers(const short* __restrict__ he,
                                                  short* __restrict__ T8) {
  const int idx = blockIdx.x * 256 + threadIdx.x;  // 320000
  const int r = idx >> 4, d0 = (idx & 15) * 8;
  float s[8];
#pragma unroll
  for (int q = 0; q < 8; ++q) s[q] = 0.f;
#pragma unroll
  for (int j = 0; j < 8; ++j) {
    short8 x = *(const short8*)&he[(size_t)j * NN * DD + (size_t)r * DD + d0];
#pragma unroll
    for (int q = 0; q < 8; ++q) s[q] += bf2f(x[q]);
  }
  short8 o;
#pragma unroll
  for (int q = 0; q < 8; ++q) o[q] = f2bf(s[q]);
  *(short8*)&T8[(size_t)r * DD + d0] = o;
}

// ================= Kernel B1: algebraic stencil aggregation ================
__global__ __launch_bounds__(256, 3) void aggregate(
    const short* __restrict__ he, const short* __restrict__ T8,
    short* __restrict__ catb) {
  const int t = threadIdx.x;
  const int v = blockIdx.x * 16 + (t >> 4);
  const int d0 = (t & 15) * 8;
  float at[8], an[8];
#pragma unroll
  for (int q = 0; q < 8; ++q) {
    at[q] = 0.f;
    an[q] = 0.f;
  }
#pragma unroll
  for (int s = -8; s <= -1; ++s) {
    int r = v + s;
    if (r < 0) r += NN;
    short8 x = *(const short8*)&T8[(size_t)r * DD + d0];
#pragma unroll
    for (int q = 0; q < 8; ++q) an[q] += bf2f(x[q]);
  }
  {
    short8 x = *(const short8*)&T8[(size_t)v * DD + d0];
#pragma unroll
    for (int q = 0; q < 8; ++q) {
      const float f = bf2f(x[q]);
      an[q] += f;
      at[q] += f;
    }
  }
#pragma unroll
  for (int s = 1; s <= 7; ++s) {
    int r = v + s;
    if (r >= NN) r -= NN;
#pragma unroll
    for (int jj = 1; jj <= 8 - s; ++jj) {
      short8 x = *(const short8*)&he[(size_t)(jj - 1) * NN * DD +
                                     (size_t)r * DD + d0];
#pragma unroll
      for (int q = 0; q < 8; ++q) an[q] += bf2f(x[q]);
    }
  }
#pragma unroll
  for (int jj = 1; jj <= 8; ++jj) {
    int r = v - jj;
    if (r < 0) r += NN;
    short8 x = *(const short8*)&he[(size_t)(jj - 1) * NN * DD +
                                   (size_t)r * DD + d0];
#pragma unroll
    for (int q = 0; q < 8; ++q) at[q] += bf2f(x[q]);
  }
  short8 o1, o2;
#pragma unroll
  for (int q = 0; q < 8; ++q) {
    o1[q] = f2bf(at[q]);
    o2[q] = f2bf(an[q] - at[q]);
  }
  *(short8*)&catb[(size_t)v * 256 + d0] = o1;
  *(short8*)&catb[(size_t)v * 256 + 128 + d0] = o2;
}

// ======== R1-style helpers (LDS Xs/H1s, XOR swizzle) for fuse/out ==========
template <int NK, int LDX>
__device__ __forceinline__ void stage1s(const short* Xs, short* H1s,
                                        const short* __restrict__ W1t,
                                        const float* __restrict__ b1, int lane,
                                        int wid) {
  constexpr int K1 = NK * 32;
  const int lr = lane & 15, lg = lane >> 4;
#pragma unroll
  for (int ct = 0; ct < 4; ++ct) {
    const int wc = wid * 64 + ct * 16;
    short8 aw[NK];
#pragma unroll
    for (int kk = 0; kk < NK; ++kk)
      aw[kk] = *(const short8*)&W1t[(wc + lr) * K1 + kk * 32 + lg * 8];
    const f32x4 bias = *(const f32x4*)&b1[wc + 4 * lg];
#pragma unroll
    for (int r = 0; r < 4; ++r) {
      const int row = r * 16 + lr;
      const int swz = SWZ(row);
      short8 bx[NK];
#pragma unroll
      for (int kk = 0; kk < NK; ++kk)
        bx[kk] = *(const short8*)&Xs[row * LDX + ((kk * 32 + lg * 8) ^ swz)];
      f32x4 acc = bias;
#pragma unroll
      for (int kk = 0; kk < NK; ++kk) acc = MFMA(aw[kk], bx[kk], acc);
      short4v o;
#pragma unroll
      for (int q = 0; q < 4; ++q) {
        float v = acc[q] > 0.f ? acc[q] : 0.f;
        o[q] = f2bf(v);
      }
      *(short4v*)&H1s[row * 256 + ((wc + 4 * lg) ^ swz)] = o;
    }
  }
}

__device__ __forceinline__ void stage2s(const short* H1s,
                                        const short* __restrict__ W2t,
                                        f32x4 (&acc)[2][4], int lane, int wid) {
  const int lr = lane & 15, lg = lane >> 4;
#pragma unroll
  for (int ct = 0; ct < 2; ++ct) {
    const int wc = wid * 32 + ct * 16;
    short8 aw[8];
#pragma unroll
    for (int kk = 0; kk < 8; ++kk)
      aw[kk] = *(const short8*)&W2t[(wc + lr) * 256 + kk * 32 + lg * 8];
#pragma unroll
    for (int r = 0; r < 4; ++r) {
      const int row = r * 16 + lr;
      const int swz = SWZ(row);
#pragma unroll
      for (int kk = 0; kk < 8; ++kk) {
        short8 bh = *(const short8*)&H1s[row * 256 + ((kk * 32 + lg * 8) ^ swz)];
        acc[ct][r] = MFMA(aw[kk], bh, acc[ct][r]);
      }
    }
  }
}

// ================= Kernel C: t = MLP_f(cat) + h @ W_r + b_r ================
__global__ __launch_bounds__(256) void fuse_mlp(
    const short* __restrict__ catb, const short* __restrict__ hbf,
    const short* __restrict__ Wf1t, const float* __restrict__ bf1,
    const short* __restrict__ Wf2t, const float* __restrict__ bf2,
    const short* __restrict__ Wrt, const float* __restrict__ br,
    short* __restrict__ tout) {
  __shared__ __align__(16) short Xs[64][256];
  __shared__ __align__(16) short H1s[64][256];
  const int t = threadIdx.x;
  const int vbase = blockIdx.x * 64;
  {
    const int r = t >> 2, sub = t & 3;
    const int v = vbase + r;
    const bool valid = v < NN;
    const int swz = SWZ(r);
#pragma unroll
    for (int c = 0; c < 8; ++c) {
      const int d0 = sub * 64 + c * 8;
      short8 x = valid ? *(const short8*)&catb[(size_t)v * 256 + d0] : zero8();
      *(short8*)&Xs[r][d0 ^ swz] = x;
    }
  }
  __syncthreads();
  const int lane = t & 63, wid = t >> 6;
  stage1s<8, 256>(&Xs[0][0], &H1s[0][0], Wf1t, bf1, lane, wid);
  __syncthreads();
  const int lr = lane & 15, lg = lane >> 4;
  f32x4 acc[2][4];
#pragma unroll
  for (int ct = 0; ct < 2; ++ct) {
    const int wc = wid * 32 + ct * 16 + 4 * lg;
    f32x4 b0 = *(const f32x4*)&br[wc];
    f32x4 b1v = *(const f32x4*)&bf2[wc];
    f32x4 bias = b0 + b1v;
#pragma unroll
    for (int r = 0; r < 4; ++r) acc[ct][r] = bias;
  }
#pragma unroll
  for (int ct = 0; ct < 2; ++ct) {
    const int wc = wid * 32 + ct * 16;
    short8 aw[4];
#pragma unroll
    for (int kk = 0; kk < 4; ++kk)
      aw[kk] = *(const short8*)&Wrt[(wc + lr) * DD + kk * 32 + lg * 8];
#pragma unroll
    for (int r = 0; r < 4; ++r) {
      int v = vbase + r * 16 + lr;
      if (v >= NN) v = 0;
#pragma unroll
      for (int kk = 0; kk < 4; ++kk) {
        short8 bh = *(const short8*)&hbf[(size_t)v * DD + kk * 32 + lg * 8];
        acc[ct][r] = MFMA(aw[kk], bh, acc[ct][r]);
      }
    }
  }
  stage2s(&H1s[0][0], Wf2t, acc, lane, wid);
#pragma unroll
  for (int ct = 0; ct < 2; ++ct)
#pragma unroll
    for (int r = 0; r < 4; ++r) {
      const int v = vbase + r * 16 + lr;
      if (v < NN) {
        short4v o;
#pragma unroll
        for (int q = 0; q < 4; ++q) o[q] = f2bf(acc[ct][r][q]);
        *(short4v*)&tout[(size_t)v * DD + wid * 32 + ct * 16 + 4 * lg] = o;
      }
    }
}

// ================= Kernel D: out = MLP_p(t), fp32 out ======================
__global__ __launch_bounds__(256) void out_mlp(
    const short* __restrict__ tin, const short* __restrict__ Wp1t,
    const float* __restrict__ bp1, const short* __restrict__ Wp2t,
    const float* __restrict__ bp2, float* __restrict__ out) {
  __shared__ __align__(16) short Xs[64][128];
  __shared__ __align__(16) short H1s[64][256];
  const int t = threadIdx.x;
  const int vbase = blockIdx.x * 64;
  {
    const int r = t >> 2, sub = t & 3;
    const int v = vbase + r;
    const bool valid = v < NN;
    const int swz = SWZ(r);
#pragma unroll
    for (int c = 0; c < 4; ++c) {
      const int d0 = (sub * 4 + c) * 8;
      short8 x = valid ? *(const short8*)&tin[(size_t)v * DD + d0] : zero8();
      *(short8*)&Xs[r][d0 ^ swz] = x;
    }
  }
  __syncthreads();
  const int lane = t & 63, wid = t >> 6;
  stage1s<4, 128>(&Xs[0][0], &H1s[0][0], Wp1t, bp1, lane, wid);
  __syncthreads();
  const int lr = lane & 15, lg = lane >> 4;
  f32x4 acc[2][4];
#pragma unroll
  for (int ct = 0; ct < 2; ++ct) {
    const f32x4 bias = *(const f32x4*)&bp2[wid * 32 + ct * 16 + 4 * lg];
#pragma unroll
    for (int r = 0; r < 4; ++r) acc[ct][r] = bias;
  }
  stage2s(&H1s[0][0], Wp2t, acc, lane, wid);
#pragma unroll
  for (int ct = 0; ct < 2; ++ct)
#pragma unroll
    for (int r = 0; r < 4; ++r) {
      const int v = vbase + r * 16 + lr;
      if (v < NN)
        *(f32x4*)&out[(size_t)v * DD + wid * 32 + ct * 16 + 4 * lg] = acc[ct][r];
    }
}

// ================= conversions =============================================
__global__ __launch_bounds__(256) void cvt_h(const float* __restrict__ src,
                                             short* __restrict__ dst) {
  const size_t id = (size_t)(blockIdx.x * 256 + threadIdx.x) * 8;
  float4 a = *(const float4*)&src[id];
  float4 b = *(const float4*)&src[id + 4];
  short8 o;
  o[0] = f2bf(a.x); o[1] = f2bf(a.y); o[2] = f2bf(a.z); o[3] = f2bf(a.w);
  o[4] = f2bf(b.x); o[5] = f2bf(b.y); o[6] = f2bf(b.z); o[7] = f2bf(b.w);
  *(short8*)&dst[id] = o;
}

// sigma: slot s -> logical mid index (preserves bits >=5)
__device__ __forceinline__ int klog_of_slot(int s) {
  return ((s >> 5) << 5) + (((s >> 2) & 1) << 4) + (((s >> 3) & 3) << 2) + (s & 3);
}

// pool layout (shorts):
//   [0]      wqA: 4 x We1 quarter [64 mids][128 k] chunk-swz   = 32768
//   [32768]  wqB: 4 x We2 quarter [128 o][64 slots] swz+sigma  = 32768
//   [65536]  Wf1t [256][256] k-contig, pi-folded rows
//   [131072] Wf2t [128][256] k-contig
//   [163840] Wrt  [128][128] k-contig
//   [180224] Wp1t [256][128] k-contig
//   [212992] Wp2t [128][256] k-contig                          (ends 245760)
// be1P: float[256] in separate region; ids 245760..246015 fill it.
__global__ __launch_bounds__(256) void cvt_weights(
    const float* __restrict__ We1, const float* __restrict__ We2,
    const float* __restrict__ Wf1, const float* __restrict__ Wf2,
    const float* __restrict__ Wr, const float* __restrict__ Wp1,
    const float* __restrict__ Wp2, const float* __restrict__ be1,
    short* __restrict__ dst, float* __restrict__ be1P) {
  const int id = blockIdx.x * 256 + threadIdx.x;
  if (id >= 245760) {
    const int s = id - 245760;
    be1P[s] = be1[klog_of_slot(s)];
    return;
  }
  float v;
  if (id < 32768) {                       // wqA
    const int p = id >> 13, r = id & 8191;
    const int lm = r >> 7, e = r & 127;
    const int k = (((e >> 3) ^ (lm & 15)) << 3) | (e & 7);
    v = We1[k * 256 + p * 64 + lm];
  } else if (id < 65536) {                // wqB
    const int l = id - 32768;
    const int p = l >> 13, i2 = l & 8191;
    const int o = i2 >> 6, e = i2 & 63;
    const int s = (((e >> 3) ^ (o & 7)) << 3) | (e & 7);
    v = We2[(p * 64 + klog_of_slot(s)) * 128 + o];
  } else if (id < 131072) {               // Wf1t (pi-folded rows)
    const int l = id - 65536;
    const int k = l & 255, m = l >> 8;
    const int kb = k & 127;
    const int lk = (((kb >> 2) & 7) << 4) | (((kb >> 5) & 3) << 2) | (kb & 3);
    v = Wf1[(lk + (k & 128)) * 256 + m];
  } else if (id < 163840) {               // Wf2t
    const int l = id - 131072;
    v = Wf2[(l & 255) * 128 + (l >> 8)];
  } else if (id < 180224) {               // Wrt
    const int l = id - 163840;
    v = Wr[(l & 127) * 128 + (l >> 7)];
  } else if (id < 212992) {               // Wp1t
    const int l = id - 180224;
    v = Wp1[(l & 127) * 256 + (l >> 7)];
  } else {                                // Wp2t
    const int l = id - 212992;
    v = Wp2[(l & 255) * 128 + (l >> 8)];
  }
  dst[id] = f2bf(v);
}

extern "C" void kernel_launch(void* const* d_in, const int* in_sizes, int n_in,
                              void* d_out, int out_size, void* d_ws,
                              size_t ws_size, hipStream_t stream) {
  const float* h = (const float*)d_in[0];
  const float* We1 = (const float*)d_in[4];
  const float* be1 = (const float*)d_in[5];
  const float* We2 = (const float*)d_in[6];
  const float* be2 = (const float*)d_in[7];
  const float* Wf1 = (const float*)d_in[8];
  const float* bf1 = (const float*)d_in[9];
  const float* Wf2 = (const float*)d_in[10];
  const float* bf2 = (const float*)d_in[11];
  const float* Wr = (const float*)d_in[12];
  const float* br = (const float*)d_in[13];
  const float* Wp1 = (const float*)d_in[14];
  const float* bp1 = (const float*)d_in[15];
  const float* Wp2 = (const float*)d_in[16];
  const float* bp2 = (const float*)d_in[17];

  char* ws = (char*)d_ws;
  short* hbf = (short*)ws;                      // 20000*128*2   = 5,120,000
  short* he = (short*)(ws + 5120000);           // 160000*128*2  = 40,960,000
  short* catb = (short*)(ws + 46080000);        // 20000*256*2   = 10,240,000
  short* tbuf = (short*)(ws + 56320000);        // 20000*128*2   = 5,120,000
  short* wpool = (short*)(ws + 61440000);       // 245760*2      = 491,520
  float* be1P = (float*)(ws + 61931520);        // 256*4         = 1,024
  short* wqA = wpool;
  short* wqB = wpool + 32768;
  short* Wf1t = wpool + 65536;
  short* Wf2t = Wf1t + 65536;
  short* Wrt = Wf2t + 32768;
  short* Wp1t = Wrt + 16384;
  short* Wp2t = Wp1t + 32768;
  short* G = catb;   // overlay: G dead once aggregate writes catb
  short* T8 = tbuf;  // overlay: T8 dead once fuse_mlp writes tbuf

  cvt_h<<<1250, 256, 0, stream>>>(h, hbf);
  cvt_weights<<<961, 256, 0, stream>>>(We1, We2, Wf1, Wf2, Wr, Wp1, Wp2, be1,
                                       wpool, be1P);
  g_gemm<<<(NN + 127) / 128, 256, 0, stream>>>(hbf, wqA, G);
  edge_mlp<<<NE / 128, 256, 0, stream>>>(G, wqB, be1P, be2, he);
  sum_layers<<<1250, 256, 0, stream>>>(he, T8);
  aggregate<<<NN / 16, 256, 0, stream>>>(he, T8, catb);
  fuse_mlp<<<(NN + 63) / 64, 256, 0, stream>>>(catb, hbf, Wf1t, bf1, Wf2t, bf2,
                                               Wrt, br, tbuf);
  out_mlp<<<(NN + 63) / 64, 256, 0, stream>>>(tbuf, Wp1t, bp1, Wp2t, bp2,
                                              (float*)d_out);
}